// Round 11
// baseline (99.767 us; speedup 1.0000x reference)
//
#include <hip/hip_runtime.h>
#include <math.h>

// Problem constants (B, C, H, W) = (16, 256, 64, 64), GROUPS=4, RATIO=2
#define B_   16
#define C_   256
#define H_   64
#define W_   64
#define G_   4
#define HO_  128
#define WO_  128
#define HW_  (H_ * W_)
#define HOWO_ (HO_ * WO_)

// Weights in constant address space -> uniform accesses compile to s_load.
// Layout: wconst[z][u][i2][20]:
//   [0..15] = w_off[8*vv + j(k)][i]   m = 4*vv + k, vv = 0..3, k = 0..3
//   [16..19]= w_scope[v][j(k)][32*hi + i2]
// where j(k) = (k&1) + 2*z + 4*(k>>1), u = wave (v = u&3, hi = u>>2),
// channel i = 64*v + 32*hi + i2. Only the z-relevant half of the conv
// outputs is needed per block (pixel-shuffle channel split).
__constant__ float wconst[2 * 8 * 32 * 20];   // 40 KB

__global__ __launch_bounds__(256) void prep_kernel(
    const float* __restrict__ w_off,    // (32, 256)
    const float* __restrict__ w_scope,  // (4, 8, 64)
    float* __restrict__ wout)           // = wconst backing store
{
    const int k = blockIdx.x * 256 + threadIdx.x;   // 10240 total
    if (k >= 2 * 8 * 32 * 20) return;
    const int q  = k % 20;
    const int r  = k / 20;
    const int i2 = r & 31;
    const int u  = (r >> 5) & 7;
    const int z  = r >> 8;
    const int v  = u & 3;
    const int hi = u >> 2;
    const int i  = 64 * v + 32 * hi + i2;
    float val;
    if (q < 16) {
        const int vv = q >> 2, k4 = q & 3;
        const int j  = (k4 & 1) + 2 * z + 4 * (k4 >> 1);
        val = w_off[(8 * vv + j) * 256 + i];
    } else {
        const int k4 = q - 16;
        const int j  = (k4 & 1) + 2 * z + 4 * (k4 >> 1);
        val = w_scope[v * 512 + j * 64 + 32 * hi + i2];
    }
    wout[k] = val;
}

// ---------------------------------------------------------------------------
// Fused kernel, z-split: one block per (b, h, z). 512 threads = 8 waves.
// Conv: wave u (v=u&3, hi=u>>2) owns channels [64v+32hi, +32); accumulates
//   the 16 z-relevant off channels (4 per group) + its group's 4 scope
//   channels. 2-round LDS reduction; low waves emit group-v coords.
// Sample: thread (g = tid>>7, wo = tid&127) does 64 channels of bilinear
//   taps for output row ho = 2h + z.
// Grid = 2048 -> >=2 generations at 3-4 blocks/CU: later blocks' conv
// overlaps resident blocks' sample/write drain (pipeline smoothing).
// ---------------------------------------------------------------------------
__global__ __launch_bounds__(512, 8) void fused_kernel(
    const float* __restrict__ x,        // (B, 256, 64, 64)
    const float* __restrict__ b_off,    // (32,)
    const float* __restrict__ b_scope,  // (32,)
    float* __restrict__ out)            // (B, 256, 128, 128)
{
    __shared__ float4 red[8][4][64];    // off partials, 8 KB
    __shared__ float4 auxs[4][64];      // scope partials, 4 KB
    __shared__ float4 coordbuf[4][64];  // (ix0,iy0,ix1,iy1) per wo-pair, 4 KB

    const int tid = threadIdx.x;
    const int u   = __builtin_amdgcn_readfirstlane(tid >> 6);  // wave id
    const int w   = tid & 63;                                  // pixel in row

    // XCD-bijective swizzle (2048 % 8 == 0): XCD k owns logical 256k..256k+255
    // = b in {2k, 2k+1}, all h, both z.
    const int bid = ((blockIdx.x & 7) << 8) | (blockIdx.x >> 3);
    const int z   = bid & 1;
    const int h   = (bid >> 1) & 63;
    const int b   = bid >> 7;

    const int v   = u & 3;              // group
    const int hi  = u >> 2;             // channel half

    const float* xq = x + (size_t)b * C_ * HW_ +
                      (size_t)(64 * v + 32 * hi) * HW_ + h * W_ + w;
    const int wbase0 = (z * 8 + u) * (32 * 20);   // uniform

    float offp[16];
    float scp[4];
#pragma unroll
    for (int j = 0; j < 16; ++j) offp[j] = 0.f;
#pragma unroll
    for (int j = 0; j < 4; ++j) scp[j] = 0.f;

#pragma unroll 4
    for (int i2 = 0; i2 < 32; ++i2) {
        const float xv = xq[(size_t)i2 * HW_];   // coalesced 256 B / wave
        const int wb = wbase0 + i2 * 20;         // uniform -> s_load from AS4
#pragma unroll
        for (int j = 0; j < 16; ++j) offp[j] += xv * wconst[wb + j];
#pragma unroll
        for (int j = 0; j < 4; ++j)  scp[j] += xv * wconst[wb + 16 + j];
    }

    // ---- round 1: high waves publish; low waves absorb pair partner ----
    if (hi) {
#pragma unroll
        for (int c = 0; c < 4; ++c)
            red[u][c][w] = make_float4(offp[4 * c + 0], offp[4 * c + 1],
                                       offp[4 * c + 2], offp[4 * c + 3]);
        auxs[v][w] = make_float4(scp[0], scp[1], scp[2], scp[3]);
    }
    __syncthreads();
    if (!hi) {
#pragma unroll
        for (int c = 0; c < 4; ++c) {
            const float4 p = red[u + 4][c][w];
            offp[4 * c + 0] += p.x; offp[4 * c + 1] += p.y;
            offp[4 * c + 2] += p.z; offp[4 * c + 3] += p.w;
        }
        const float4 s0 = auxs[v][w];
        scp[0] += s0.x; scp[1] += s0.y; scp[2] += s0.z; scp[3] += s0.w;
        // round 2 publish
#pragma unroll
        for (int c = 0; c < 4; ++c)
            red[u][c][w] = make_float4(offp[4 * c + 0], offp[4 * c + 1],
                                       offp[4 * c + 2], offp[4 * c + 3]);
    }
    __syncthreads();
    if (!hi) {
        // wave v: its group's 4 off channels live in chunk v of each slot
        float4 a = make_float4(0.f, 0.f, 0.f, 0.f);
#pragma unroll
        for (int tt = 0; tt < 4; ++tt) {
            const float4 pa = red[tt][v][w];
            a.x += pa.x; a.y += pa.y; a.z += pa.z; a.w += pa.w;
        }
        const float ao[4] = {a.x, a.y, a.z, a.w};
        float f[4];
#pragma unroll
        for (int k = 0; k < 4; ++k) {
            const int j = (k & 1) + 2 * z + 4 * (k >> 1);
            const float offv = ao[k] + b_off[8 * v + j];
            const float scv  = scp[k] + b_scope[8 * v + j];
            f[k] = offv * 0.5f / (1.f + expf(-scv));
        }
        // coords: og0(r2) = f[r2], og1(r2) = f[2+r2]; ho = 2h+z
        const float hoF = (float)(2 * h + z);
        float ix0 = ((float)(2 * w + 0) - 0.5f + f[0]) * 0.5f;
        float iy0 = (hoF - 0.5f + f[2]) * 0.5f;
        float ix1 = ((float)(2 * w + 1) - 0.5f + f[1]) * 0.5f;
        float iy1 = (hoF - 0.5f + f[3]) * 0.5f;
        ix0 = fminf(fmaxf(ix0, 0.f), (float)(W_ - 1));
        iy0 = fminf(fmaxf(iy0, 0.f), (float)(H_ - 1));
        ix1 = fminf(fmaxf(ix1, 0.f), (float)(W_ - 1));
        iy1 = fminf(fmaxf(iy1, 0.f), (float)(H_ - 1));
        coordbuf[v][w] = make_float4(ix0, iy0, ix1, iy1);
    }
    __syncthreads();

    // ---------------- phase 2: bilinear sampling ----------------
    const int wo = tid & 127;
    const int g  = tid >> 7;            // group 0..3
    const int ho = 2 * h + z;

    const float2 c = ((const float2*)&coordbuf[g][0])[wo];
    const float ix = c.x, iy = c.y;

    const float x0f = floorf(ix);
    const float y0f = floorf(iy);
    const float wx = ix - x0f;
    const float wy = iy - y0f;
    int x0 = (int)x0f;
    int y0 = (int)y0f;
    x0 = max(0, min(x0, W_ - 1));
    y0 = max(0, min(y0, H_ - 1));
    const int x1 = min(x0 + 1, W_ - 1);
    const int y1 = min(y0 + 1, H_ - 1);

    const float w00 = (1.f - wy) * (1.f - wx);
    const float w01 = (1.f - wy) * wx;
    const float w10 = wy * (1.f - wx);
    const float w11 = wy * wx;

    const int p00 = y0 * W_ + x0;
    const int p01 = y0 * W_ + x1;
    const int p10 = y1 * W_ + x0;
    const int p11 = y1 * W_ + x1;

    const float* xb = x + (size_t)b * C_ * HW_ + (size_t)g * HW_;
    float* ob = out + (size_t)b * C_ * HOWO_ + (size_t)g * HOWO_ +
                ho * WO_ + wo;

#pragma unroll 4
    for (int cc = 0; cc < 64; ++cc) {
        const float* pl = xb + (size_t)cc * 4 * HW_;
        const float val = pl[p00] * w00 + pl[p01] * w01 +
                          pl[p10] * w10 + pl[p11] * w11;
        ob[(size_t)cc * 4 * HOWO_] = val;
    }
}

// ---------------------------------------------------------------------------
extern "C" void kernel_launch(void* const* d_in, const int* in_sizes, int n_in,
                              void* d_out, int out_size, void* d_ws, size_t ws_size,
                              hipStream_t stream) {
    const float* x       = (const float*)d_in[0];
    const float* w_off   = (const float*)d_in[1];
    const float* b_off   = (const float*)d_in[2];
    const float* w_scope = (const float*)d_in[3];
    const float* b_scope = (const float*)d_in[4];
    float* out = (float*)d_out;

    void* wsym = nullptr;
    (void)hipGetSymbolAddress(&wsym, HIP_SYMBOL(wconst));

    prep_kernel<<<dim3(40), 256, 0, stream>>>(w_off, w_scope, (float*)wsym);
    fused_kernel<<<dim3(2 * B_ * H_), 512, 0, stream>>>(x, b_off, b_scope, out);
}

// Round 12
// 78.410 us; speedup vs baseline: 1.2724x; 1.2724x over previous
//
#include <hip/hip_runtime.h>
#include <math.h>

// Problem constants (B, C, H, W) = (16, 256, 64, 64), GROUPS=4, RATIO=2
#define B_   16
#define C_   256
#define H_   64
#define W_   64
#define G_   4
#define HO_  128
#define WO_  128
#define HW_  (H_ * W_)
#define HOWO_ (HO_ * WO_)

// Weights in constant address space -> uniform accesses compile to s_load.
__constant__ float wconst[8 * 32 * 40];   // 40 KB

// ---------------------------------------------------------------------------
// Prep: wcomb[u][i2][40] for wave u (v=u&3, hi=u>>2), channel i=64v+32hi+i2:
//   [0..31]  = w_off[o][i]                     o = 0..31
//   [32..39] = w_scope[v][j][32*hi + i2]       j = 0..7
// ---------------------------------------------------------------------------
__global__ __launch_bounds__(256) void prep_kernel(
    const float* __restrict__ w_off,    // (32, 256)
    const float* __restrict__ w_scope,  // (4, 8, 64)
    float* __restrict__ wout)           // = wconst backing store
{
    const int k = blockIdx.x * 256 + threadIdx.x;   // 10240 total
    if (k >= 8 * 32 * 40) return;
    const int q  = k % 40;
    const int r  = k / 40;
    const int i2 = r & 31;
    const int u  = r >> 5;
    const int v  = u & 3;
    const int hi = u >> 2;
    const int i  = 64 * v + 32 * hi + i2;
    float val;
    if (q < 32) val = w_off[q * 256 + i];
    else        val = w_scope[v * 512 + (q - 32) * 64 + 32 * hi + i2];
    wout[k] = val;
}

// ---------------------------------------------------------------------------
// Fused kernel (R9 verbatim; only change: nontemporal output stores).
// Grid = 1024, XCD-bijective swizzle; 512 threads = 8 waves per block.
// ---------------------------------------------------------------------------
__global__ __launch_bounds__(512, 6) void fused_kernel(
    const float* __restrict__ x,        // (B, 256, 64, 64)
    const float* __restrict__ b_off,    // (32,)
    const float* __restrict__ b_scope,  // (32,)
    float* __restrict__ out)            // (B, 256, 128, 128)
{
    __shared__ float4 red[8][8][64];    // [slot][chunk][pixel] 32 KB
    __shared__ float4 aux[8][64];       // scp partials, then coords; 8 KB

    const int tid = threadIdx.x;
    const int u   = __builtin_amdgcn_readfirstlane(tid >> 6);  // wave id
    const int w   = tid & 63;                                  // pixel in row

    // XCD-bijective swizzle: XCD k owns b in {2k, 2k+1}, all h.
    const int bid = ((blockIdx.x & 7) << 7) | (blockIdx.x >> 3);
    const int h   = bid & 63;
    const int b   = bid >> 6;

    const int v   = u & 3;              // group
    const int hi  = u >> 2;             // channel half

    const float* xq = x + (size_t)b * C_ * HW_ +
                      (size_t)(64 * v + 32 * hi) * HW_ + h * W_ + w;
    const int wbase0 = u * (32 * 40);   // uniform

    float offp[32];
    float scp[8];
#pragma unroll
    for (int j = 0; j < 32; ++j) offp[j] = 0.f;
#pragma unroll
    for (int j = 0; j < 8; ++j) scp[j] = 0.f;

#pragma unroll 4
    for (int i2 = 0; i2 < 32; ++i2) {
        const float xv = xq[(size_t)i2 * HW_];   // coalesced 256 B / wave
        const int wb = wbase0 + i2 * 40;         // uniform -> s_load from AS4
#pragma unroll
        for (int j = 0; j < 32; ++j) offp[j] += xv * wconst[wb + j];
#pragma unroll
        for (int j = 0; j < 8; ++j)  scp[j] += xv * wconst[wb + 32 + j];
    }

    // ---- round 1: high waves publish; low waves absorb pair partner ----
    if (hi) {
#pragma unroll
        for (int j = 0; j < 8; ++j)
            red[4 + v][j][w] = make_float4(offp[4 * j + 0], offp[4 * j + 1],
                                           offp[4 * j + 2], offp[4 * j + 3]);
        aux[2 * v + 0][w] = make_float4(scp[0], scp[1], scp[2], scp[3]);
        aux[2 * v + 1][w] = make_float4(scp[4], scp[5], scp[6], scp[7]);
    }
    __syncthreads();
    if (!hi) {
#pragma unroll
        for (int j = 0; j < 8; ++j) {
            const float4 p = red[4 + v][j][w];
            offp[4 * j + 0] += p.x; offp[4 * j + 1] += p.y;
            offp[4 * j + 2] += p.z; offp[4 * j + 3] += p.w;
        }
        const float4 s0 = aux[2 * v + 0][w];
        const float4 s1 = aux[2 * v + 1][w];
        scp[0] += s0.x; scp[1] += s0.y; scp[2] += s0.z; scp[3] += s0.w;
        scp[4] += s1.x; scp[5] += s1.y; scp[6] += s1.z; scp[7] += s1.w;
        // round 2 publish
#pragma unroll
        for (int j = 0; j < 8; ++j)
            red[v][j][w] = make_float4(offp[4 * j + 0], offp[4 * j + 1],
                                       offp[4 * j + 2], offp[4 * j + 3]);
    }
    __syncthreads();
    if (!hi) {
        float4 a = make_float4(0.f, 0.f, 0.f, 0.f);
        float4 c = make_float4(0.f, 0.f, 0.f, 0.f);
#pragma unroll
        for (int tt = 0; tt < 4; ++tt) {
            const float4 pa = red[tt][2 * v + 0][w];
            const float4 pc = red[tt][2 * v + 1][w];
            a.x += pa.x; a.y += pa.y; a.z += pa.z; a.w += pa.w;
            c.x += pc.x; c.y += pc.y; c.z += pc.z; c.w += pc.w;
        }
        const float ao[8] = {a.x, a.y, a.z, a.w, c.x, c.y, c.z, c.w};
        float f[8];
#pragma unroll
        for (int j = 0; j < 8; ++j) {
            const float offv = ao[j] + b_off[8 * v + j];
            const float scv  = scp[j] + b_scope[8 * v + j];
            f[j] = offv * 0.5f / (1.f + expf(-scv));
        }
        // coords for group v: aux[2v+r1][w] = (ix0,iy0,ix1,iy1) for wo=2w,2w+1
#pragma unroll
        for (int r1 = 0; r1 < 2; ++r1) {
            const float hoF = (float)(2 * h + r1);
            float ix0 = ((float)(2 * w + 0) - 0.5f + f[2 * r1 + 0]) * 0.5f;
            float iy0 = (hoF - 0.5f + f[4 + 2 * r1 + 0]) * 0.5f;
            float ix1 = ((float)(2 * w + 1) - 0.5f + f[2 * r1 + 1]) * 0.5f;
            float iy1 = (hoF - 0.5f + f[4 + 2 * r1 + 1]) * 0.5f;
            ix0 = fminf(fmaxf(ix0, 0.f), (float)(W_ - 1));
            iy0 = fminf(fmaxf(iy0, 0.f), (float)(H_ - 1));
            ix1 = fminf(fmaxf(ix1, 0.f), (float)(W_ - 1));
            iy1 = fminf(fmaxf(iy1, 0.f), (float)(H_ - 1));
            aux[2 * v + r1][w] = make_float4(ix0, iy0, ix1, iy1);
        }
    }
    __syncthreads();

    // ---------------- phase 2: bilinear sampling ----------------
    const int wo = tid & 127;
    const int z  = (tid >> 7) & 1;
    const int gh = tid >> 8;            // group half
    const int ho = 2 * h + z;

    const float2* cbase = (const float2*)&aux[0][0];
    const float* xb0 = x + (size_t)b * C_ * HW_;
    float* ob0 = out + (size_t)b * C_ * HOWO_ + ho * WO_ + wo;

#pragma unroll
    for (int gg = 0; gg < 2; ++gg) {
        const int g = 2 * gh + gg;
        const float2 c = cbase[(g * 2 + z) * 128 + wo];
        const float ix = c.x, iy = c.y;

        const float x0f = floorf(ix);
        const float y0f = floorf(iy);
        const float wx = ix - x0f;
        const float wy = iy - y0f;
        int x0 = (int)x0f;
        int y0 = (int)y0f;
        x0 = max(0, min(x0, W_ - 1));
        y0 = max(0, min(y0, H_ - 1));
        const int x1 = min(x0 + 1, W_ - 1);
        const int y1 = min(y0 + 1, H_ - 1);

        const float w00 = (1.f - wy) * (1.f - wx);
        const float w01 = (1.f - wy) * wx;
        const float w10 = wy * (1.f - wx);
        const float w11 = wy * wx;

        const int p00 = y0 * W_ + x0;
        const int p01 = y0 * W_ + x1;
        const int p10 = y1 * W_ + x0;
        const int p11 = y1 * W_ + x1;

        const float* xb = xb0 + (size_t)g * HW_;
        float* ob = ob0 + (size_t)g * HOWO_;

#pragma unroll 4
        for (int cc = 0; cc < 64; ++cc) {
            const float* pl = xb + (size_t)cc * 4 * HW_;
            const float val = pl[p00] * w00 + pl[p01] * w01 +
                              pl[p10] * w10 + pl[p11] * w11;
            // out is write-once/never-read: nontemporal keeps L2/L3 for x
            __builtin_nontemporal_store(val, &ob[(size_t)cc * 4 * HOWO_]);
        }
    }
}

// ---------------------------------------------------------------------------
extern "C" void kernel_launch(void* const* d_in, const int* in_sizes, int n_in,
                              void* d_out, int out_size, void* d_ws, size_t ws_size,
                              hipStream_t stream) {
    const float* x       = (const float*)d_in[0];
    const float* w_off   = (const float*)d_in[1];
    const float* b_off   = (const float*)d_in[2];
    const float* w_scope = (const float*)d_in[3];
    const float* b_scope = (const float*)d_in[4];
    float* out = (float*)d_out;

    void* wsym = nullptr;
    (void)hipGetSymbolAddress(&wsym, HIP_SYMBOL(wconst));

    prep_kernel<<<dim3(40), 256, 0, stream>>>(w_off, w_scope, (float*)wsym);
    fused_kernel<<<dim3(B_ * H_), 512, 0, stream>>>(x, b_off, b_scope, out);
}